// Round 10
// baseline (291.414 us; speedup 1.0000x reference)
//
#include <hip/hip_runtime.h>
#include <hip/hip_bf16.h>

#define N_TOT  8192
#define B_HALF 4096
#define D_DIM  256
#define MFIX   192.0f /* fixed softmax shift, log2 domain */

typedef short bf16x8 __attribute__((ext_vector_type(8)));
typedef float f32x4  __attribute__((ext_vector_type(4)));

#define NEG_INF (-__builtin_inff())
#define RSCALE  1.6986436f     /* sqrt(2*log2e): scaled dot = logits in log2 units */
#define LN2F    0.69314718056f

__device__ __forceinline__ float exp2_fast(float x) {
  float r;
  asm("v_exp_f32 %0, %1" : "=v"(r) : "v"(x));
  return r;
}

__device__ __forceinline__ unsigned short f2b(float f) {
  __hip_bfloat16 h = __float2bfloat16(f);
  return *reinterpret_cast<unsigned short*>(&h);
}

// reps = [zjs; zis]*RSCALE bf16; zero out/counter/s_arr/m_arr (ws re-poisoned each launch).
__global__ __launch_bounds__(256) void convert_k(const float* __restrict__ zis,
                                                 const float* __restrict__ zjs,
                                                 unsigned short* __restrict__ reps,
                                                 float* __restrict__ out,
                                                 int* __restrict__ counter,
                                                 float* __restrict__ s_arr,
                                                 unsigned* __restrict__ m_arr) {
  size_t idx = ((size_t)blockIdx.x * 256 + threadIdx.x) * 4;
  const float* src = (idx < (size_t)B_HALF * D_DIM) ? (zjs + idx)
                                                    : (zis + (idx - (size_t)B_HALF * D_DIM));
  float4 v = *reinterpret_cast<const float4*>(src);
  ushort4 o;
  o.x = f2b(v.x * RSCALE); o.y = f2b(v.y * RSCALE);
  o.z = f2b(v.z * RSCALE); o.w = f2b(v.w * RSCALE);
  *reinterpret_cast<ushort4*>(reps + idx) = o;
  if (blockIdx.x < 32)       s_arr[blockIdx.x * 256 + threadIdx.x] = 0.0f;
  else if (blockIdx.x < 64)  m_arr[(blockIdx.x - 32) * 256 + threadIdx.x] = 0u;
  if (blockIdx.x == 64 && threadIdx.x < 2) out[threadIdx.x] = 0.0f;
  if (blockIdx.x == 64 && threadIdx.x == 2) *counter = 0;
}

#define G2L(srcp, ldsp)                                                          \
  __builtin_amdgcn_global_load_lds(                                              \
      (const __attribute__((address_space(1))) void*)(srcp),                     \
      (__attribute__((address_space(3))) void*)(ldsp), 16, 0, 0)

// Barrier-free steady state: block = one 64-col B strip (staged once, 32KB LDS)
// x 2048 rows. 4 waves; wave = 8 private panels of 64 rows. A streamed from L2.
// Grid 512 = 128 strips x 4 rowgroups; 3 blocks/CU co-resident, all in one round.
__global__ __launch_bounds__(256, 3) void ntxent_main(const unsigned short* __restrict__ reps,
                                                      float* __restrict__ s_arr,
                                                      unsigned* __restrict__ m_arr,
                                                      float* __restrict__ pos_out,
                                                      int* __restrict__ counter,
                                                      float* __restrict__ out) {
  __shared__ short Bs[64 * 256];   // [col][K] 32 KB, chunk-XOR layout

  const int tid  = threadIdx.x;
  const int lane = tid & 63;
  const int l15  = lane & 15;
  const int l4   = lane >> 4;
  const int wave = tid >> 6;

  // XCD-clustered mapping: XCD x owns strips [16x, 16x+16), all rowgroups.
  const int xcd   = (int)blockIdx.x & 7;
  const int idx   = (int)blockIdx.x >> 3;        // 0..63
  const int strip = xcd * 16 + (idx & 15);       // 0..127
  const int rg    = idx >> 4;                    // 0..3
  const int C0    = strip * 64;

  // ---- stage B strip once: 64 cols x 256 K = 2048 chunks; linear LDS dest,
  // XOR-swizzled source chunk (involution, both-sides rule 21) ----
#pragma unroll
  for (int it = 0; it < 8; ++it) {
    const int cid = it * 256 + tid;
    const int col = cid >> 5, ch = cid & 31;
    const int swz = (ch & 24) | ((ch ^ col) & 7);
    const unsigned short* src = reps + (size_t)(C0 + col) * D_DIM + swz * 8;
    G2L(src, &Bs[cid * 8]);
  }
  __syncthreads();   // drains vmcnt; last sync until block end

  const int rowbase = rg * 2048 + wave * 512;

  // A row base pointers (per mf), lane-resolved; ks advances by 32 shorts
  const unsigned short* aRow[4];
#pragma unroll
  for (int mf = 0; mf < 4; ++mf)
    aRow[mf] = reps + (size_t)(rowbase + mf * 16 + l15) * D_DIM + l4 * 8;

#define LOAD_A(dst, ks)                                                          \
  do {                                                                           \
    _Pragma("unroll") for (int mf_ = 0; mf_ < 4; ++mf_)                          \
      dst[mf_] = *reinterpret_cast<const bf16x8*>(aRow[mf_] + poff + (ks) * 32); \
  } while (0)

#define READ_B(ks)                                                               \
  do {                                                                           \
    _Pragma("unroll") for (int nf_ = 0; nf_ < 4; ++nf_) {                        \
      const int col_ = nf_ * 16 + l15;                                           \
      const int c_   = (ks) * 4 + l4;                                            \
      const int ch_  = (c_ & 24) | ((c_ ^ col_) & 7);                            \
      bfr[nf_] = *reinterpret_cast<const bf16x8*>(&Bs[col_ * 256 + ch_ * 8]);    \
    }                                                                            \
  } while (0)

#define MFMA_ALL(CUR)                                                            \
  do {                                                                           \
    _Pragma("unroll") for (int mf_ = 0; mf_ < 4; ++mf_)                          \
      _Pragma("unroll") for (int nf_ = 0; nf_ < 4; ++nf_)                        \
        acc[mf_][nf_] = __builtin_amdgcn_mfma_f32_16x16x32_bf16(                 \
            CUR[mf_], bfr[nf_], acc[mf_][nf_], 0, 0, 0);                         \
  } while (0)

#define KS_STEP(ks, CUR, NXT)                                                    \
  do {                                                                           \
    if ((ks) < 7) LOAD_A(NXT, (ks) + 1);                                         \
    READ_B(ks);                                                                  \
    MFMA_ALL(CUR);                                                               \
  } while (0)

#pragma unroll 1
  for (int p = 0; p < 8; ++p) {
    const int row0 = rowbase + p * 64;
    const int poff = p * 64 * D_DIM;   // shorts offset for this panel's rows

    f32x4 acc[4][4];
    const f32x4 vz = {0.f, 0.f, 0.f, 0.f};
#pragma unroll
    for (int mf = 0; mf < 4; ++mf)
#pragma unroll
      for (int nf = 0; nf < 4; ++nf) acc[mf][nf] = vz;

    bf16x8 afA[4], afB[4], bfr[4];
    LOAD_A(afA, 0);
    KS_STEP(0, afA, afB); KS_STEP(1, afB, afA);
    KS_STEP(2, afA, afB); KS_STEP(3, afB, afA);
    KS_STEP(4, afA, afB); KS_STEP(5, afB, afA);
    KS_STEP(6, afA, afB); KS_STEP(7, afB, afA);

    // diag / positive handling (each lands in exactly one strip per row panel)
    const bool spd = (C0 == row0);                        // mask self-similarity
    const bool spp = (C0 == ((row0 + B_HALF) & (N_TOT - 1)));  // capture positive
    if (spd | spp) {
#pragma unroll
      for (int mf = 0; mf < 4; ++mf)
#pragma unroll
        for (int r = 0; r < 4; ++r)
          if (l15 == l4 * 4 + r) {
            if (spd) acc[mf][mf][r] = NEG_INF;
            else pos_out[row0 + mf * 16 + l15] = acc[mf][mf][r];
          }
    }

    // fixed-M streamed softmax: per-lane partials, 16-lane merge, atomic deposit
#pragma unroll
    for (int mf = 0; mf < 4; ++mf)
#pragma unroll
      for (int r = 0; r < 4; ++r) {
        float u0 = acc[mf][0][r], u1 = acc[mf][1][r];
        float u2 = acc[mf][2][r], u3 = acc[mf][3][r];
        float m = fmaxf(fmaxf(u0, u1), fmaxf(u2, u3));
        float s = exp2_fast(u0 - MFIX) + exp2_fast(u1 - MFIX)
                + exp2_fast(u2 - MFIX) + exp2_fast(u3 - MFIX);
#pragma unroll
        for (int off = 1; off < 16; off <<= 1) {
          s += __shfl_xor(s, off, 16);
          m = fmaxf(m, __shfl_xor(m, off, 16));
        }
        if (l15 == 0) {
          const int row = row0 + mf * 16 + l4 * 4 + r;
          atomicAdd(&s_arr[row], s);
          atomicMax(&m_arr[row], __float_as_uint(m));   // row max > 0 in practice
        }
      }
  }

  // completion protocol: last block finalizes (r8-proven)
  __threadfence();
  __syncthreads();
  __shared__ int isLast;
  if (tid == 0) isLast = (atomicAdd(counter, 1) == 511) ? 1 : 0;
  __syncthreads();
  if (isLast) {
    __threadfence();
    float L = 0.f, H = 0.f;
    for (int row = tid; row < N_TOT; row += 256) {
      const float ss  = s_arr[row];
      const float m   = __uint_as_float(m_arr[row]);
      const float pos = pos_out[row];
      L += (MFIX + __log2f(ss) - pos);
      H += (pos >= m) ? 1.0f : 0.0f;
    }
    L *= LN2F;
#pragma unroll
    for (int off = 32; off; off >>= 1) {
      L += __shfl_down(L, off);
      H += __shfl_down(H, off);
    }
    float* redf = reinterpret_cast<float*>(Bs);
    if ((tid & 63) == 0) { redf[wave * 2] = L; redf[wave * 2 + 1] = H; }
    __syncthreads();
    if (tid == 0) {
      float Lt = 0.f, Ht = 0.f;
#pragma unroll
      for (int w = 0; w < 4; ++w) { Lt += redf[w * 2]; Ht += redf[w * 2 + 1]; }
      out[0] = Lt * (1.0f / 8192.0f);
      out[1] = Ht * (1.0f / 8192.0f);
    }
  }
}

extern "C" void kernel_launch(void* const* d_in, const int* in_sizes, int n_in,
                              void* d_out, int out_size, void* d_ws, size_t ws_size,
                              hipStream_t stream) {
  const float* zis = (const float*)d_in[0];
  const float* zjs = (const float*)d_in[1];
  float* out = (float*)d_out;

  char* ws = (char*)d_ws;
  unsigned short* reps = (unsigned short*)ws;                        // 4 MB
  float*    s_arr = (float*)   (ws + 4u * 1024u * 1024u);            // 32 KB
  unsigned* m_arr = (unsigned*)(ws + 4u * 1024u * 1024u + 32u * 1024u);
  float*    pos_a = (float*)   (ws + 4u * 1024u * 1024u + 64u * 1024u);
  int*      cnt   = (int*)     (ws + 4u * 1024u * 1024u + 96u * 1024u);
  (void)in_sizes; (void)n_in; (void)out_size; (void)ws_size;

  convert_k<<<2048, 256, 0, stream>>>(zis, zjs, reps, out, cnt, s_arr, m_arr);
  ntxent_main<<<512, 256, 0, stream>>>(reps, s_arr, m_arr, pos_a, cnt, out);
}